// Round 14
// baseline (848.874 us; speedup 1.0000x reference)
//
#include <hip/hip_runtime.h>
#include <hip/hip_cooperative_groups.h>

namespace cg = cooperative_groups;

#define D 128
#define CACHE 8    // fallback path only (deg > 64; actual max deg ~45)
#define BSH 8      // bucket = 256 consecutive dsts -> nbk<=256, in-block scans
#define BCAP 8192  // csr_build LDS staging (avg bucket ~4350, max ~4700)
#define CPAD 16    // one counter per 64B line (atomic line-contention fix, R9)
#define SCH 4096   // edges per scatter/hist block

#define GEMM_LDS 33792   // 4*16*132*4
#define SCAT_LDS 35840   // SCH*4*2 + 3*256*4
#define CSR_LDS  36864   // BCAP*4 + 4*256*4
#define MEGA_LDS 36864   // max of all phases

typedef __attribute__((ext_vector_type(8))) short bf16x8;
typedef __attribute__((ext_vector_type(4))) float f32x4;

__device__ __forceinline__ unsigned short f2b(float f) {   // f32 -> bf16 (RNE)
    unsigned u = __float_as_uint(f);
    return (unsigned short)((u + 0x7fffu + ((u >> 16) & 1u)) >> 16);
}

// ================= phase bodies (R13-proven code, parameterized by unit id) =================

__device__ void zero_phase(int G, int* __restrict__ bcnt, int* __restrict__ bcur,
                           float* __restrict__ sumexp, float* __restrict__ out0) {
    for (int t = blockIdx.x * 256 + threadIdx.x; t < 256 * CPAD; t += G * 256) {
        bcnt[t] = 0;
        bcur[t] = 0;
    }
    if (blockIdx.x == 0 && threadIdx.x == 0) {
        *sumexp = 0.f;
        *out0 = 0.f;
    }
}

__device__ void hist_body(char* smem, int b, const int* __restrict__ ad, int E, int n,
                          int* __restrict__ bcnt) {
    int* scnt = (int*)smem;
    int t = threadIdx.x;
    int Et = E + n;
    int base = b * SCH;
    int m = min(SCH, Et - base);
    scnt[t] = 0;
    __syncthreads();
    for (int i = t; i < m; i += 256) {
        int e = base + i;
        int dst = (e < E) ? ad[E + e] : (e - E);
        atomicAdd(&scnt[dst >> BSH], 1);
    }
    __syncthreads();
    if (scnt[t]) atomicAdd(&bcnt[t * CPAD], scnt[t]);
}

__device__ void conv_body(int b, const float* __restrict__ in, unsigned short* __restrict__ out,
                          int count8) {
    int i = b * 256 + threadIdx.x;
    if (i < count8) {                       // guard, no return (mega loops have barriers)
        const float4* p = (const float4*)(in + (size_t)i * 8);
        float4 a = p[0], bb = p[1];
        bf16x8 o;
        o[0] = (short)f2b(a.x);  o[1] = (short)f2b(a.y);
        o[2] = (short)f2b(a.z);  o[3] = (short)f2b(a.w);
        o[4] = (short)f2b(bb.x); o[5] = (short)f2b(bb.y);
        o[6] = (short)f2b(bb.z); o[7] = (short)f2b(bb.w);
        *(bf16x8*)(out + (size_t)i * 8) = o;
    }
}

__device__ void pack_unit(const float* __restrict__ W, unsigned short* __restrict__ Wp, int idx) {
    int j  = idx & 7;
    int l  = (idx >> 3) & 63;
    int ks = (idx >> 9) & 3;
    int ct = idx >> 11;
    int k = ks * 32 + ((l >> 4) << 3) + j;
    int c = ct * 16 + (l & 15);
    Wp[idx] = f2b(W[(size_t)k * D + c]);
}

__device__ void gemm_body(char* smem, int bid, const unsigned short* __restrict__ xb,
                          const unsigned short* __restrict__ Wp,
                          const float* __restrict__ a_src, const float* __restrict__ a_dst,
                          unsigned short* __restrict__ h16,
                          float* __restrict__ as_, float* __restrict__ ad_, int n) {
    float (*lds)[16][132] = (float (*)[16][132])smem;
    int wv = threadIdx.x >> 6;
    int lane = threadIdx.x & 63;
    int base = bid * 64 + wv * 16;
    int arow = base + (lane & 15);
    if (arow >= n) arow = n - 1;
    const bf16x8* aptr = (const bf16x8*)(xb + (size_t)arow * D + ((lane >> 4) << 3));
    const bf16x8* bp = (const bf16x8*)Wp;

    f32x4 acc[8];
#pragma unroll
    for (int ct = 0; ct < 8; ++ct) acc[ct] = (f32x4){0.f, 0.f, 0.f, 0.f};

#pragma unroll
    for (int ks = 0; ks < 4; ++ks) {
        bf16x8 af = aptr[ks * 4];
#pragma unroll
        for (int ct = 0; ct < 8; ++ct) {
            bf16x8 bf_ = bp[(ct * 4 + ks) * 64 + lane];
            acc[ct] = __builtin_amdgcn_mfma_f32_16x16x32_bf16(af, bf_, acc[ct], 0, 0, 0);
        }
    }

    int r0 = (lane >> 4) * 4;
    int c0 = lane & 15;
#pragma unroll
    for (int ct = 0; ct < 8; ++ct)
#pragma unroll
        for (int i = 0; i < 4; ++i)
            lds[wv][r0 + i][ct * 16 + c0] = acc[ct][i];
    __syncthreads();

#pragma unroll
    for (int i = 0; i < 4; ++i) {
        int r = (lane >> 4) + i * 4;
        int gr = base + r;
        if (gr < n) {
            const float* row = lds[wv][r];
            bf16x8 o;
#pragma unroll
            for (int j = 0; j < 8; ++j) o[j] = (short)f2b(row[c0 * 8 + j]);
            *(bf16x8*)(h16 + (size_t)gr * D + c0 * 8) = o;
        }
    }

    int r = lane >> 2, q = lane & 3;
    float s1 = 0.f, s2 = 0.f;
    const float* row = lds[wv][r];
#pragma unroll
    for (int c = 0; c < 32; ++c) {
        float hv = row[q * 32 + c];
        s1 = fmaf(hv, a_src[q * 32 + c], s1);
        s2 = fmaf(hv, a_dst[q * 32 + c], s2);
    }
    s1 += __shfl_xor(s1, 1); s1 += __shfl_xor(s1, 2);
    s2 += __shfl_xor(s2, 1); s2 += __shfl_xor(s2, 2);
    int gr = base + r;
    if (q == 0 && gr < n) { as_[gr] = s1; ad_[gr] = s2; }
}

__device__ void scatter_body(char* smem, int sb, const int* __restrict__ ad, int E, int n,
                             const int* __restrict__ bcnt, int* __restrict__ bcur,
                             unsigned* __restrict__ pairbuf, int nbk) {
    unsigned* es = (unsigned*)smem;          // SCH
    unsigned* bp = es + SCH;                 // SCH
    int* cnt  = (int*)(bp + SCH);            // 256
    int* gofs = cnt + 256;                   // 256
    int* bs   = gofs + 256;                  // 256
    int t = threadIdx.x;
    int v = (t < nbk) ? bcnt[t * CPAD] : 0;
    bs[t] = v;
    __syncthreads();
    for (int off = 1; off < 256; off <<= 1) {
        int o = (t >= off) ? bs[t - off] : 0;
        __syncthreads();
        bs[t] += o;
        __syncthreads();
    }
    int incl = bs[t];
    __syncthreads();
    bs[t] = incl - v;                        // exclusive base
    cnt[t] = 0;
    __syncthreads();

    int Et = E + n;
    int base = sb * SCH;
    int m = min(SCH, Et - base);
    for (int i = t; i < m; i += 256) {
        int e = base + i;
        int src, dst;
        if (e < E) { src = ad[e]; dst = ad[E + e]; }
        else       { src = dst = e - E; }
        int b = dst >> BSH;
        int lpos = atomicAdd(&cnt[b], 1);
        es[i] = ((unsigned)src << BSH) | (unsigned)(dst & 255);
        bp[i] = ((unsigned)b << 16) | (unsigned)lpos;
    }
    __syncthreads();
    gofs[t] = cnt[t] ? atomicAdd(&bcur[t * CPAD], cnt[t]) : 0;
    __syncthreads();
    for (int i = t; i < m; i += 256) {
        unsigned vv = bp[i];
        int b = vv >> 16;
        int lpos = vv & 0xffff;
        pairbuf[bs[b] + gofs[b] + lpos] = es[i];
    }
}

__device__ void csr_body(char* smem, int b, const unsigned* __restrict__ pairbuf,
                         const int* __restrict__ bcnt, int* __restrict__ deg,
                         int* __restrict__ startv, int* __restrict__ csr_src, int nbk, int n) {
    unsigned* es = (unsigned*)smem;          // BCAP
    int* bs  = (int*)(es + BCAP);            // 256
    int* h   = bs + 256;
    int* sc  = h + 256;
    int* cur = sc + 256;
    int t = threadIdx.x;
    int v = (t < nbk) ? bcnt[t * CPAD] : 0;
    bs[t] = v;
    __syncthreads();
    for (int off = 1; off < 256; off <<= 1) {
        int o = (t >= off) ? bs[t - off] : 0;
        __syncthreads();
        bs[t] += o;
        __syncthreads();
    }
    int lo = bs[b] - bcnt[b * CPAD];
    int cnt = bcnt[b * CPAD];
    h[t] = 0;
    __syncthreads();
    for (int i = t; i < cnt; i += 256) {
        unsigned p = pairbuf[lo + i];
        if (i < BCAP) es[i] = p;
        atomicAdd(&h[p & 255], 1);
    }
    __syncthreads();
    sc[t] = h[t];
    __syncthreads();
    for (int off = 1; off < 256; off <<= 1) {
        int v2 = (t >= off) ? sc[t - off] : 0;
        __syncthreads();
        sc[t] += v2;
        __syncthreads();
    }
    int node = (b << BSH) + t;
    if (node < n) {
        deg[node] = h[t];
        startv[node] = lo + sc[t] - h[t];
    }
    cur[t] = 0;
    __syncthreads();
    for (int i = t; i < cnt; i += 256) {
        unsigned p = (i < BCAP) ? es[i] : pairbuf[lo + i];
        int dloc = p & 255;
        int pos = atomicAdd(&cur[dloc], 1);
        csr_src[lo + (sc[dloc] - h[dloc]) + pos] = (int)(p >> BSH);
    }
}

// per-node edge softmax + gather + bias + relu (+ L2 head-li fusion); 1 wave per node
__device__ void agg_body(int g, const int* __restrict__ csr_src, const int* __restrict__ startv,
                         const int* __restrict__ deg, const float* __restrict__ as_,
                         const float* __restrict__ ad_, const unsigned short* __restrict__ h16,
                         const float* __restrict__ bias, unsigned short* __restrict__ out16,
                         float* __restrict__ xout, float* __restrict__ sout,
                         const float* __restrict__ w_lin, const float* __restrict__ b_lin,
                         const int* __restrict__ resmask, float* __restrict__ pr,
                         const int* __restrict__ num_res, int n) {
    int wid = threadIdx.x >> 6;
    int lane = threadIdx.x & 63;
    int node = g * 4 + wid;
    if (node >= n) return;                    // no block-level barriers below -> safe
    int s0 = startv[node];
    int dg = deg[node];
    float adv = ad_[node];

    float acc0 = 0.f, acc1 = 0.f;

    if (dg <= 64) {
        bool ok = lane < dg;
        int sj = ok ? csr_src[s0 + lane] : 0;
        float v = -3.4e38f;
        if (ok) {
            v = as_[sj] + adv;
            v = v >= 0.f ? v : 0.2f * v;
        }
        float m = v;
        for (int off = 32; off; off >>= 1) m = fmaxf(m, __shfl_xor(m, off));
        float e = ok ? __expf(v - m) : 0.f;
        float ds = e;
        for (int off = 32; off; off >>= 1) ds += __shfl_xor(ds, off);
        float inv = 1.f / (ds + 1e-16f);

        int mc8 = (dg + 7) & ~7;
        for (int l = 0; l < mc8; l += 8) {
            float a[8];
            int   tt[8];
            unsigned hh[8];
#pragma unroll
            for (int k = 0; k < 8; ++k) {
                a[k]  = __shfl(e, l + k);
                tt[k] = __shfl(sj, l + k);
            }
#pragma unroll
            for (int k = 0; k < 8; ++k)
                hh[k] = *(const unsigned*)(h16 + (size_t)tt[k] * D + lane * 2);
#pragma unroll
            for (int k = 0; k < 8; ++k) {
                acc0 = fmaf(a[k], __uint_as_float(hh[k] << 16), acc0);
                acc1 = fmaf(a[k], __uint_as_float(hh[k] & 0xffff0000u), acc1);
            }
        }
        acc0 *= inv;
        acc1 *= inv;
    } else {
        float vreg[CACHE];
        int   sreg[CACHE];
        float m = -3.4e38f;
#pragma unroll
        for (int c = 0; c < CACHE; ++c) {
            int j = c * 64 + lane;
            bool ok = j < dg;
            int s = ok ? csr_src[s0 + j] : 0;
            sreg[c] = s;
            float v = -3.4e38f;
            if (ok) {
                v = as_[s] + adv;
                v = v >= 0.f ? v : 0.2f * v;
            }
            vreg[c] = v;
            m = fmaxf(m, v);
        }
        for (int off = 32; off; off >>= 1) m = fmaxf(m, __shfl_xor(m, off));
        float dsum = 0.f;
#pragma unroll
        for (int c = 0; c < CACHE; ++c) {
            int j = c * 64 + lane;
            float e = (j < dg) ? __expf(vreg[c] - m) : 0.f;
            vreg[c] = e;
            dsum += e;
        }
        for (int off = 32; off; off >>= 1) dsum += __shfl_xor(dsum, off);
        float inv = 1.f / (dsum + 1e-16f);
#pragma unroll
        for (int c = 0; c < CACHE; ++c) {
            if (c * 64 < dg) {
                int mc = min(64, dg - c * 64);
                for (int l = 0; l < mc; ++l) {
                    float a   = __shfl(vreg[c], l) * inv;
                    int  srcj = __shfl(sreg[c], l);
                    unsigned hv = *(const unsigned*)(h16 + (size_t)srcj * D + lane * 2);
                    acc0 = fmaf(a, __uint_as_float(hv << 16), acc0);
                    acc1 = fmaf(a, __uint_as_float(hv & 0xffff0000u), acc1);
                }
            }
        }
    }

    float2 bv = *(const float2*)(bias + lane * 2);
    float o0 = acc0 + bv.x, o1 = acc1 + bv.y;
    o0 = o0 > 0.f ? o0 : 0.f;
    o1 = o1 > 0.f ? o1 : 0.f;

    if (out16) {
        ushort2 u2;
        u2.x = f2b(o0);
        u2.y = f2b(o1);
        *(ushort2*)(out16 + (size_t)node * D + lane * 2) = u2;
    } else {
        *(float2*)(xout + (size_t)node * D + lane * 2) = make_float2(o0, o1);
        if (node < num_res[0])
            *(float2*)(sout + (size_t)node * D + lane * 2) = make_float2(o0, o1);
        float2 wv = *(const float2*)(w_lin + lane * 2);
        float part = fmaf(o0, wv.x, o1 * wv.y);
        for (int off = 32; off; off >>= 1) part += __shfl_xor(part, off);
        if (lane == 0) {
            float s = part + b_lin[0];
            if (resmask[node] == 0) s = -1000000000.0f;
            pr[node] = s;
        }
    }
}

__device__ void hexp_phase(int G, float* __restrict__ pr, float* __restrict__ sumexp,
                           const int* __restrict__ resmask, float* __restrict__ maskf, int n) {
    float acc = 0.f;
    for (int i = blockIdx.x * 256 + threadIdx.x; i < n; i += G * 256) {
        float u = __expf(pr[i]);
        pr[i] = u;
        maskf[i] = (float)resmask[i];
        acc += u;
    }
    for (int off = 32; off; off >>= 1) acc += __shfl_down(acc, off);
    if ((threadIdx.x & 63) == 0) atomicAdd(sumexp, acc);
}

__device__ void hfinal_phase(int G, float* __restrict__ pr, const float* __restrict__ sumexp,
                             const float* __restrict__ res, float* __restrict__ out0, int n) {
    float se = *sumexp;
    float lt = 0.f;
    for (int i = blockIdx.x * 256 + threadIdx.x; i < n; i += G * 256) {
        float p = pr[i] / se;
        pr[i] = p;
        float pc = fminf(fmaxf(p, 1e-10f), 1.0f);
        lt += -logf(pc) * res[i];
    }
    for (int off = 32; off; off >>= 1) lt += __shfl_down(lt, off);
    if ((threadIdx.x & 63) == 0) atomicAdd(out0, lt);
}

// ================= cooperative mega-kernel: whole pipeline, 8 grid syncs =================
__global__ __launch_bounds__(256, 4) void mega(
        const float* in, unsigned short* xb16,
        const float* W1, unsigned short* Wp1, const float* W2, unsigned short* Wp2,
        const int* ad, int E, int n,
        int* bcnt, int* bcur, unsigned* pairbuf,
        int* deg, int* startv, int* csr_src,
        unsigned short* h16, float* as_, float* ad_,
        const float* a_src1, const float* a_dst1, const float* b1,
        const float* a_src2, const float* a_dst2, const float* b2,
        const float* w_lin, const float* b_lin,
        const int* resmask, const float* res, const int* num_res,
        float* sumexp, float* out0, float* prob, float* xout, float* maskf, float* sout,
        int nbk, int nbhist, int nbconv, int count8, int ggrid, int ngroups) {
    extern __shared__ char smem[];
    cg::grid_group grid = cg::this_grid();
    int G = (int)gridDim.x;

    // P0: zero counters/scalars
    zero_phase(G, bcnt, bcur, sumexp, out0);
    __threadfence(); grid.sync();

    // P1: bucket hist || conv f32->bf16 || pack W1/W2
    int totalP1 = nbhist + nbconv + 128;
    for (int u = blockIdx.x; u < totalP1; u += G) {
        if (u < nbhist) hist_body(smem, u, ad, E, n, bcnt);
        else if (u < nbhist + nbconv) conv_body(u - nbhist, in, xb16, count8);
        else if (u < nbhist + nbconv + 64) pack_unit(W1, Wp1, (u - nbhist - nbconv) * 256 + threadIdx.x);
        else pack_unit(W2, Wp2, (u - nbhist - nbconv - 64) * 256 + threadIdx.x);
        __syncthreads();
    }
    __threadfence(); grid.sync();

    // P2: bucket scatter || gemm layer 1
    int totalP2 = nbhist + ggrid;
    for (int u = blockIdx.x; u < totalP2; u += G) {
        if (u < nbhist) scatter_body(smem, u, ad, E, n, bcnt, bcur, pairbuf, nbk);
        else gemm_body(smem, u - nbhist, xb16, Wp1, a_src1, a_dst1, h16, as_, ad_, n);
        __syncthreads();
    }
    __threadfence(); grid.sync();

    // P3: csr build
    for (int u = blockIdx.x; u < nbk; u += G) {
        csr_body(smem, u, pairbuf, bcnt, deg, startv, csr_src, nbk, n);
        __syncthreads();
    }
    __threadfence(); grid.sync();

    // P4: aggregate layer 1 -> xb16
    for (int g = blockIdx.x; g < ngroups; g += G)
        agg_body(g, csr_src, startv, deg, as_, ad_, h16, b1,
                 xb16, nullptr, nullptr, nullptr, nullptr, nullptr, nullptr, nullptr, n);
    __threadfence(); grid.sync();

    // P5: gemm layer 2
    for (int u = blockIdx.x; u < ggrid; u += G) {
        gemm_body(smem, u, xb16, Wp2, a_src2, a_dst2, h16, as_, ad_, n);
        __syncthreads();
    }
    __threadfence(); grid.sync();

    // P6: aggregate layer 2 -> d_out (+ fused head li)
    for (int g = blockIdx.x; g < ngroups; g += G)
        agg_body(g, csr_src, startv, deg, as_, ad_, h16, b2,
                 nullptr, xout, sout, w_lin, b_lin, resmask, prob, num_res, n);
    __threadfence(); grid.sync();

    // P7: head exp + sum
    hexp_phase(G, prob, sumexp, resmask, maskf, n);
    __threadfence(); grid.sync();

    // P8: head final (prob normalize + loss)
    hfinal_phase(G, prob, sumexp, res, out0, n);
}

// ================= fallback multi-kernel wrappers (R13 chain) =================

__global__ void k_zero(int* bcnt, int* bcur, float* sumexp, float* out0) {
    int t = blockIdx.x * blockDim.x + threadIdx.x;
    if (t < 256 * CPAD) { bcnt[t] = 0; bcur[t] = 0; }
    if (t == 0) { *sumexp = 0.f; *out0 = 0.f; }
}

__global__ void k_prep(const float* in, unsigned short* out,
                       const float* W1, unsigned short* Wp1,
                       const float* W2, unsigned short* Wp2,
                       const int* ad, int E, int n, int* bcnt,
                       int count8, int nbconv, int nbhist) {
    __shared__ int scnt[256];
    int b = blockIdx.x;
    if (b < nbhist) hist_body((char*)scnt, b, ad, E, n, bcnt);
    else if (b < nbhist + nbconv) conv_body(b - nbhist, in, out, count8);
    else if (b < nbhist + nbconv + 64) pack_unit(W1, Wp1, (b - nbhist - nbconv) * 256 + threadIdx.x);
    else pack_unit(W2, Wp2, (b - nbhist - nbconv - 64) * 256 + threadIdx.x);
}

__global__ __launch_bounds__(256) void k_gemm1_scatter(
        const unsigned short* xb, const unsigned short* Wp,
        const float* a_src, const float* a_dst,
        unsigned short* h16, float* as_, float* ad_,
        const int* ad, int E, const int* bcnt, int* bcur,
        unsigned* pairbuf, int nbk, int n, int ggrid) {
    extern __shared__ char smem[];
    if ((int)blockIdx.x < ggrid)
        gemm_body(smem, blockIdx.x, xb, Wp, a_src, a_dst, h16, as_, ad_, n);
    else
        scatter_body(smem, blockIdx.x - ggrid, ad, E, n, bcnt, bcur, pairbuf, nbk);
}

__global__ __launch_bounds__(256) void k_csr(const unsigned* pairbuf, const int* bcnt,
                                             int* deg, int* startv, int* csr_src, int nbk, int n) {
    extern __shared__ char smem[];
    csr_body(smem, blockIdx.x, pairbuf, bcnt, deg, startv, csr_src, nbk, n);
}

__global__ void k_agg(const int* csr_src, const int* startv, const int* deg,
                      const float* as_, const float* ad_, const unsigned short* h16,
                      const float* bias, unsigned short* out16,
                      float* xout, float* sout, const float* w_lin, const float* b_lin,
                      const int* resmask, float* pr, const int* num_res, int n) {
    agg_body(blockIdx.x, csr_src, startv, deg, as_, ad_, h16, bias, out16,
             xout, sout, w_lin, b_lin, resmask, pr, num_res, n);
}

__global__ __launch_bounds__(256) void k_gemm(const unsigned short* xb, const unsigned short* Wp,
                                              const float* a_src, const float* a_dst,
                                              unsigned short* h16, float* as_, float* ad_, int n) {
    extern __shared__ char smem[];
    gemm_body(smem, blockIdx.x, xb, Wp, a_src, a_dst, h16, as_, ad_, n);
}

__global__ void k_hexp(float* pr, float* sumexp, const int* resmask, float* maskf, int n) {
    hexp_phase(gridDim.x, pr, sumexp, resmask, maskf, n);
}

__global__ void k_hfinal(float* pr, const float* sumexp, const float* res, float* out0, int n) {
    hfinal_phase(gridDim.x, pr, sumexp, res, out0, n);
}

extern "C" void kernel_launch(void* const* d_in, const int* in_sizes, int n_in,
                              void* d_out, int out_size, void* d_ws, size_t ws_size,
                              hipStream_t stream) {
    const float* input_node = (const float*)d_in[0];
    const int*   inputad    = (const int*)d_in[1];
    const float* res        = (const float*)d_in[2];
    const int*   resmask    = (const int*)d_in[3];
    const int*   num_res    = (const int*)d_in[4];
    const float* W1     = (const float*)d_in[5];
    const float* a_src1 = (const float*)d_in[6];
    const float* a_dst1 = (const float*)d_in[7];
    const float* b1     = (const float*)d_in[8];
    const float* W2     = (const float*)d_in[9];
    const float* a_src2 = (const float*)d_in[10];
    const float* a_dst2 = (const float*)d_in[11];
    const float* b2     = (const float*)d_in[12];
    const float* w_lin  = (const float*)d_in[13];
    const float* b_lin  = (const float*)d_in[14];

    int n = in_sizes[0] / D;
    int E = in_sizes[1] / 2;
    int Et = E + n;
    int nbk = (n + 255) >> BSH;

    // workspace carve
    char* w = (char*)d_ws;
    unsigned short* xb16 = (unsigned short*)w; w += (size_t)n * D * 2;
    unsigned short* h16  = (unsigned short*)w; w += (size_t)n * D * 2;
    unsigned short* Wp1 = (unsigned short*)w; w += 16384 * 2;
    unsigned short* Wp2 = (unsigned short*)w; w += 16384 * 2;
    float* as_   = (float*)w; w += (size_t)n * 4;
    float* ad_   = (float*)w; w += (size_t)n * 4;
    int*   deg   = (int*)w;   w += (size_t)n * 4;
    int*   startv= (int*)w;   w += (size_t)n * 4;
    int*   csr_src=(int*)w;   w += (size_t)Et * 4;
    unsigned* pairbuf = (unsigned*)w; w += (size_t)Et * 4;
    int*   bcnt  = (int*)w;   w += 256 * CPAD * 4;
    int*   bcur  = (int*)w;   w += 256 * CPAD * 4;
    float* sumexp = (float*)w; w += 8;

    // d_out carve
    float* out0  = (float*)d_out;
    float* prob  = out0 + 1;
    float* xout  = prob + n;
    float* maskf = xout + (size_t)n * D;
    float* sout  = maskf + n;

    auto cdiv = [](long long a, long long b) { return (int)((a + b - 1) / b); };
    int count8 = n * D / 8;
    int nbconv = cdiv(count8, 256);
    int nbhist = cdiv(Et, SCH);
    int ggrid  = cdiv(n, 64);
    int ngroups = cdiv(n, 4);
    int nb = cdiv(n, 256);

    // ---- try cooperative mega-kernel ----
    int maxb = 0;
    hipError_t oe = hipOccupancyMaxActiveBlocksPerMultiprocessor(&maxb, mega, 256, (size_t)MEGA_LDS);
    int G = (oe == hipSuccess && maxb > 0) ? maxb * 256 : 0;   // 256 CUs on MI355X
    if (G > 1024) G = 1024;
    bool coop_ok = false;
    if (G > 0) {
        void* args[] = {
            (void*)&input_node, (void*)&xb16,
            (void*)&W1, (void*)&Wp1, (void*)&W2, (void*)&Wp2,
            (void*)&inputad, (void*)&E, (void*)&n,
            (void*)&bcnt, (void*)&bcur, (void*)&pairbuf,
            (void*)&deg, (void*)&startv, (void*)&csr_src,
            (void*)&h16, (void*)&as_, (void*)&ad_,
            (void*)&a_src1, (void*)&a_dst1, (void*)&b1,
            (void*)&a_src2, (void*)&a_dst2, (void*)&b2,
            (void*)&w_lin, (void*)&b_lin,
            (void*)&resmask, (void*)&res, (void*)&num_res,
            (void*)&sumexp, (void*)&out0, (void*)&prob, (void*)&xout, (void*)&maskf, (void*)&sout,
            (void*)&nbk, (void*)&nbhist, (void*)&nbconv, (void*)&count8, (void*)&ggrid, (void*)&ngroups
        };
        hipError_t le = hipLaunchCooperativeKernel(mega, dim3(G), dim3(256), args,
                                                   (unsigned)MEGA_LDS, stream);
        coop_ok = (le == hipSuccess);
    }

    if (!coop_ok) {
        // ---- fallback: R13 multi-kernel chain ----
        dim3 blk(256);
        k_zero<<<32, blk, 0, stream>>>(bcnt, bcur, sumexp, out0);
        k_prep<<<nbhist + nbconv + 128, blk, 0, stream>>>(input_node, xb16, W1, Wp1, W2, Wp2,
                                                          inputad, E, n, bcnt, count8, nbconv, nbhist);
        k_gemm1_scatter<<<ggrid + nbhist, blk, SCAT_LDS, stream>>>(
            xb16, Wp1, a_src1, a_dst1, h16, as_, ad_,
            inputad, E, bcnt, bcur, pairbuf, nbk, n, ggrid);
        k_csr<<<nbk, blk, CSR_LDS, stream>>>(pairbuf, bcnt, deg, startv, csr_src, nbk, n);
        k_agg<<<ngroups, blk, 0, stream>>>(csr_src, startv, deg, as_, ad_, h16, b1,
                                           xb16, nullptr, nullptr, nullptr, nullptr,
                                           nullptr, nullptr, nullptr, n);
        k_gemm<<<ggrid, blk, GEMM_LDS, stream>>>(xb16, Wp2, a_src2, a_dst2, h16, as_, ad_, n);
        k_agg<<<ngroups, blk, 0, stream>>>(csr_src, startv, deg, as_, ad_, h16, b2,
                                           nullptr, xout, sout, w_lin, b_lin,
                                           resmask, prob, num_res, n);
        k_hexp<<<nb, blk, 0, stream>>>(prob, sumexp, resmask, maskf, n);
        k_hfinal<<<nb, blk, 0, stream>>>(prob, sumexp, res, out0, n);
    }
}

// Round 15
// 181.674 us; speedup vs baseline: 4.6725x; 4.6725x over previous
//
#include <hip/hip_runtime.h>

#define D 128
#define CACHE 8    // fallback path only (deg > 64; actual max deg ~45)
#define BSH 8      // bucket = 256 consecutive dsts -> nbk<=256, in-block scans
#define BCAP 8192  // csr_build LDS staging (avg bucket ~4350, max ~4700)
#define CPAD 16    // one counter per 64B line (atomic line-contention fix, R9)
#define SCH 4096   // edges per scatter/hist block

#define GEMM_LDS 33792   // 4*16*132*4
#define SCAT_LDS 35840   // SCH*4*2 + 3*256*4
#define CSR_LDS  36864   // BCAP*4 + 4*256*4

typedef __attribute__((ext_vector_type(8))) short bf16x8;
typedef __attribute__((ext_vector_type(4))) float f32x4;

__device__ __forceinline__ unsigned short f2b(float f) {   // f32 -> bf16 (RNE)
    unsigned u = __float_as_uint(f);
    return (unsigned short)((u + 0x7fffu + ((u >> 16) & 1u)) >> 16);
}

// ---------------- parallel zero-init ----------------
__global__ void zero_init(int* __restrict__ bcnt, int* __restrict__ bcur,
                          float* __restrict__ sumexp, float* __restrict__ out0) {
    int t = blockIdx.x * blockDim.x + threadIdx.x;
    if (t < 256 * CPAD) {
        bcnt[t] = 0;
        bcur[t] = 0;
    }
    if (t == 0) {
        *sumexp = 0.f;
        *out0 = 0.f;
    }
}

// ---------------- fused: chunked LDS bucket-hist + conv_bf16 + pack_w1/w2 ----------------
__device__ __forceinline__ void pack_body(const float* __restrict__ W,
                                          unsigned short* __restrict__ Wp, int idx) {
    int j  = idx & 7;
    int l  = (idx >> 3) & 63;
    int ks = (idx >> 9) & 3;
    int ct = idx >> 11;
    int k = ks * 32 + ((l >> 4) << 3) + j;
    int c = ct * 16 + (l & 15);
    Wp[idx] = f2b(W[(size_t)k * D + c]);
}

__global__ void prep(const float* __restrict__ in, unsigned short* __restrict__ out,
                     const float* __restrict__ W1, unsigned short* __restrict__ Wp1,
                     const float* __restrict__ W2, unsigned short* __restrict__ Wp2,
                     const int* __restrict__ ad, int E, int n, int* __restrict__ bcnt,
                     int count8, int nbconv, int nbhist) {
    __shared__ int scnt[256];
    int b = blockIdx.x;
    int t = threadIdx.x;
    if (b < nbhist) {                          // chunked bucket histogram (block-aggregated)
        int Et = E + n;
        int base = b * SCH;
        int m = min(SCH, Et - base);
        scnt[t] = 0;
        __syncthreads();
        for (int i = t; i < m; i += 256) {
            int e = base + i;
            int dst = (e < E) ? ad[E + e] : (e - E);
            atomicAdd(&scnt[dst >> BSH], 1);
        }
        __syncthreads();
        if (scnt[t]) atomicAdd(&bcnt[t * CPAD], scnt[t]);
    } else if (b < nbhist + nbconv) {          // x f32 -> bf16
        int i = (b - nbhist) * 256 + t;
        if (i >= count8) return;
        const float4* p = (const float4*)(in + (size_t)i * 8);
        float4 a = p[0], bb = p[1];
        bf16x8 o;
        o[0] = (short)f2b(a.x);  o[1] = (short)f2b(a.y);
        o[2] = (short)f2b(a.z);  o[3] = (short)f2b(a.w);
        o[4] = (short)f2b(bb.x); o[5] = (short)f2b(bb.y);
        o[6] = (short)f2b(bb.z); o[7] = (short)f2b(bb.w);
        *(bf16x8*)(out + (size_t)i * 8) = o;
    } else if (b < nbhist + nbconv + 64) {
        pack_body(W1, Wp1, (b - nbhist - nbconv) * 256 + t);
    } else {
        pack_body(W2, Wp2, (b - nbhist - nbconv - 64) * 256 + t);
    }
}

// ---------------- MFMA GEMM body (dynamic LDS) ----------------
__device__ void gemm_body(char* smem, int bid, const unsigned short* __restrict__ xb,
                          const unsigned short* __restrict__ Wp,
                          const float* __restrict__ a_src, const float* __restrict__ a_dst,
                          unsigned short* __restrict__ h16,
                          float* __restrict__ as_, float* __restrict__ ad_, int n) {
    float (*lds)[16][132] = (float (*)[16][132])smem;   // [4][16][132]
    int wv = threadIdx.x >> 6;
    int lane = threadIdx.x & 63;
    int base = bid * 64 + wv * 16;
    int arow = base + (lane & 15);
    if (arow >= n) arow = n - 1;
    const bf16x8* aptr = (const bf16x8*)(xb + (size_t)arow * D + ((lane >> 4) << 3));
    const bf16x8* bp = (const bf16x8*)Wp;

    f32x4 acc[8];
#pragma unroll
    for (int ct = 0; ct < 8; ++ct) acc[ct] = (f32x4){0.f, 0.f, 0.f, 0.f};

#pragma unroll
    for (int ks = 0; ks < 4; ++ks) {
        bf16x8 af = aptr[ks * 4];
#pragma unroll
        for (int ct = 0; ct < 8; ++ct) {
            bf16x8 bf_ = bp[(ct * 4 + ks) * 64 + lane];
            acc[ct] = __builtin_amdgcn_mfma_f32_16x16x32_bf16(af, bf_, acc[ct], 0, 0, 0);
        }
    }

    int r0 = (lane >> 4) * 4;
    int c0 = lane & 15;
#pragma unroll
    for (int ct = 0; ct < 8; ++ct)
#pragma unroll
        for (int i = 0; i < 4; ++i)
            lds[wv][r0 + i][ct * 16 + c0] = acc[ct][i];
    __syncthreads();

#pragma unroll
    for (int i = 0; i < 4; ++i) {
        int r = (lane >> 4) + i * 4;
        int gr = base + r;
        if (gr < n) {
            const float* row = lds[wv][r];
            bf16x8 o;
#pragma unroll
            for (int j = 0; j < 8; ++j) o[j] = (short)f2b(row[c0 * 8 + j]);
            *(bf16x8*)(h16 + (size_t)gr * D + c0 * 8) = o;
        }
    }

    int r = lane >> 2, q = lane & 3;
    float s1 = 0.f, s2 = 0.f;
    const float* row = lds[wv][r];
#pragma unroll
    for (int c = 0; c < 32; ++c) {
        float hv = row[q * 32 + c];
        s1 = fmaf(hv, a_src[q * 32 + c], s1);
        s2 = fmaf(hv, a_dst[q * 32 + c], s2);
    }
    s1 += __shfl_xor(s1, 1); s1 += __shfl_xor(s1, 2);
    s2 += __shfl_xor(s2, 1); s2 += __shfl_xor(s2, 2);
    int gr = base + r;
    if (q == 0 && gr < n) { as_[gr] = s1; ad_[gr] = s2; }
}

__global__ __launch_bounds__(256) void gemm_mfma(const unsigned short* __restrict__ xb,
                                                 const unsigned short* __restrict__ Wp,
                                                 const float* __restrict__ a_src,
                                                 const float* __restrict__ a_dst,
                                                 unsigned short* __restrict__ h16,
                                                 float* __restrict__ as_, float* __restrict__ ad_,
                                                 int n) {
    extern __shared__ char smem[];
    gemm_body(smem, blockIdx.x, xb, Wp, a_src, a_dst, h16, as_, ad_, n);
}

// ---------------- block-aggregated bucket scatter (in-block bbase scan) ----------------
__device__ void scatter_body(char* smem, int sb, const int* __restrict__ ad, int E, int n,
                             const int* __restrict__ bcnt, int* __restrict__ bcur,
                             unsigned* __restrict__ pairbuf, int nbk) {
    unsigned* es = (unsigned*)smem;          // SCH
    unsigned* bp = es + SCH;                 // SCH
    int* cnt  = (int*)(bp + SCH);            // 256
    int* gofs = cnt + 256;                   // 256
    int* bs   = gofs + 256;                  // 256
    int t = threadIdx.x;
    int v = (t < nbk) ? bcnt[t * CPAD] : 0;
    bs[t] = v;
    __syncthreads();
    for (int off = 1; off < 256; off <<= 1) {
        int o = (t >= off) ? bs[t - off] : 0;
        __syncthreads();
        bs[t] += o;
        __syncthreads();
    }
    int incl = bs[t];
    __syncthreads();
    bs[t] = incl - v;                        // exclusive base
    cnt[t] = 0;
    __syncthreads();

    int Et = E + n;
    int base = sb * SCH;
    int m = min(SCH, Et - base);
    for (int i = t; i < m; i += 256) {
        int e = base + i;
        int src, dst;
        if (e < E) { src = ad[e]; dst = ad[E + e]; }
        else       { src = dst = e - E; }
        int b = dst >> BSH;
        int lpos = atomicAdd(&cnt[b], 1);
        es[i] = ((unsigned)src << BSH) | (unsigned)(dst & 255);
        bp[i] = ((unsigned)b << 16) | (unsigned)lpos;
    }
    __syncthreads();
    gofs[t] = cnt[t] ? atomicAdd(&bcur[t * CPAD], cnt[t]) : 0;
    __syncthreads();
    for (int i = t; i < m; i += 256) {
        unsigned vv = bp[i];
        int b = vv >> 16;
        int lpos = vv & 0xffff;
        pairbuf[bs[b] + gofs[b] + lpos] = es[i];
    }
}

// fused: gemm layer-1 (blocks [0,ggrid)) || bucket scatter (blocks [ggrid, ggrid+nbhist))
__global__ __launch_bounds__(256) void gemm1_scatter(
        const unsigned short* __restrict__ xb, const unsigned short* __restrict__ Wp,
        const float* __restrict__ a_src, const float* __restrict__ a_dst,
        unsigned short* __restrict__ h16, float* __restrict__ as_, float* __restrict__ ad_,
        const int* __restrict__ ad, int E, const int* __restrict__ bcnt, int* __restrict__ bcur,
        unsigned* __restrict__ pairbuf, int nbk, int n, int ggrid) {
    extern __shared__ char smem[];
    if ((int)blockIdx.x < ggrid)
        gemm_body(smem, blockIdx.x, xb, Wp, a_src, a_dst, h16, as_, ad_, n);
    else
        scatter_body(smem, blockIdx.x - ggrid, ad, E, n, bcnt, bcur, pairbuf, nbk);
}

// ---------------- csr_build: one block per bucket, in-block bbase scan ----------------
__global__ __launch_bounds__(256) void csr_build(const unsigned* __restrict__ pairbuf,
                                                 const int* __restrict__ bcnt,
                                                 int* __restrict__ deg, int* __restrict__ startv,
                                                 int* __restrict__ csr_src, int nbk, int n) {
    __shared__ unsigned es[BCAP];
    __shared__ int bs[256], h[256], sc[256], cur[256];
    int b = blockIdx.x;
    int t = threadIdx.x;
    int v = (t < nbk) ? bcnt[t * CPAD] : 0;
    bs[t] = v;
    __syncthreads();
    for (int off = 1; off < 256; off <<= 1) {
        int o = (t >= off) ? bs[t - off] : 0;
        __syncthreads();
        bs[t] += o;
        __syncthreads();
    }
    int lo = bs[b] - bcnt[b * CPAD];
    int cnt = bcnt[b * CPAD];
    h[t] = 0;
    __syncthreads();
    for (int i = t; i < cnt; i += 256) {
        unsigned p = pairbuf[lo + i];
        if (i < BCAP) es[i] = p;
        atomicAdd(&h[p & 255], 1);
    }
    __syncthreads();
    sc[t] = h[t];
    __syncthreads();
    for (int off = 1; off < 256; off <<= 1) {
        int v2 = (t >= off) ? sc[t - off] : 0;
        __syncthreads();
        sc[t] += v2;
        __syncthreads();
    }
    int node = (b << BSH) + t;
    if (node < n) {
        deg[node] = h[t];
        startv[node] = lo + sc[t] - h[t];
    }
    cur[t] = 0;
    __syncthreads();
    for (int i = t; i < cnt; i += 256) {
        unsigned p = (i < BCAP) ? es[i] : pairbuf[lo + i];
        int dloc = p & 255;
        int pos = atomicAdd(&cur[dloc], 1);
        csr_src[lo + (sc[dloc] - h[dloc]) + pos] = (int)(p >> BSH);
    }
}

// ------- fused per-node edge softmax + gather + bias + relu (+ L2 head-li fusion) -------
// one wave per node; uniform-readlane gather, full-wave 256B row reads, batched x8
// (x16 regressed: occupancy drop, R12 — aggregate is fetch-throughput-bound, not latency)
__global__ void gat_aggregate(const int* __restrict__ csr_src, const int* __restrict__ start,
                              const int* __restrict__ deg, const float* __restrict__ as_,
                              const float* __restrict__ ad_, const unsigned short* __restrict__ h16,
                              const float* __restrict__ bias,
                              unsigned short* __restrict__ out16,                   // L1 path
                              float* __restrict__ xout, float* __restrict__ sout,   // L2 path
                              const float* __restrict__ w_lin, const float* __restrict__ b_lin,
                              const int* __restrict__ resmask, float* __restrict__ pr,
                              const int* __restrict__ num_res, int n) {
    int wid = threadIdx.x >> 6;
    int lane = threadIdx.x & 63;
    int node = blockIdx.x * 4 + wid;
    if (node >= n) return;
    int s0 = start[node];
    int dg = deg[node];
    float adv = ad_[node];

    float acc0 = 0.f, acc1 = 0.f;

    if (dg <= 64) {
        bool ok = lane < dg;
        int sj = ok ? csr_src[s0 + lane] : 0;
        float v = -3.4e38f;
        if (ok) {
            v = as_[sj] + adv;
            v = v >= 0.f ? v : 0.2f * v;
        }
        float m = v;
        for (int off = 32; off; off >>= 1) m = fmaxf(m, __shfl_xor(m, off));
        float e = ok ? __expf(v - m) : 0.f;
        float ds = e;
        for (int off = 32; off; off >>= 1) ds += __shfl_xor(ds, off);
        float inv = 1.f / (ds + 1e-16f);

        int mc8 = (dg + 7) & ~7;
        for (int l = 0; l < mc8; l += 8) {
            float a[8];
            int   tt[8];
            unsigned hh[8];
#pragma unroll
            for (int k = 0; k < 8; ++k) {
                a[k]  = __shfl(e, l + k);
                tt[k] = __shfl(sj, l + k);
            }
#pragma unroll
            for (int k = 0; k < 8; ++k)
                hh[k] = *(const unsigned*)(h16 + (size_t)tt[k] * D + lane * 2);
#pragma unroll
            for (int k = 0; k < 8; ++k) {
                acc0 = fmaf(a[k], __uint_as_float(hh[k] << 16), acc0);
                acc1 = fmaf(a[k], __uint_as_float(hh[k] & 0xffff0000u), acc1);
            }
        }
        acc0 *= inv;
        acc1 *= inv;
    } else {
        float vreg[CACHE];
        int   sreg[CACHE];
        float m = -3.4e38f;
#pragma unroll
        for (int c = 0; c < CACHE; ++c) {
            int j = c * 64 + lane;
            bool ok = j < dg;
            int s = ok ? csr_src[s0 + j] : 0;
            sreg[c] = s;
            float v = -3.4e38f;
            if (ok) {
                v = as_[s] + adv;
                v = v >= 0.f ? v : 0.2f * v;
            }
            vreg[c] = v;
            m = fmaxf(m, v);
        }
        for (int off = 32; off; off >>= 1) m = fmaxf(m, __shfl_xor(m, off));
        float dsum = 0.f;
#pragma unroll
        for (int c = 0; c < CACHE; ++c) {
            int j = c * 64 + lane;
            float e = (j < dg) ? __expf(vreg[c] - m) : 0.f;
            vreg[c] = e;
            dsum += e;
        }
        for (int off = 32; off; off >>= 1) dsum += __shfl_xor(dsum, off);
        float inv = 1.f / (dsum + 1e-16f);
#pragma unroll
        for (int c = 0; c < CACHE; ++c) {
            if (c * 64 < dg) {
                int mc = min(64, dg - c * 64);
                for (int l = 0; l < mc; ++l) {
                    float a   = __shfl(vreg[c], l) * inv;
                    int  srcj = __shfl(sreg[c], l);
                    unsigned hv = *(const unsigned*)(h16 + (size_t)srcj * D + lane * 2);
                    acc0 = fmaf(a, __uint_as_float(hv << 16), acc0);
                    acc1 = fmaf(a, __uint_as_float(hv & 0xffff0000u), acc1);
                }
            }
        }
    }

    float2 bv = *(const float2*)(bias + lane * 2);
    float o0 = acc0 + bv.x, o1 = acc1 + bv.y;
    o0 = o0 > 0.f ? o0 : 0.f;
    o1 = o1 > 0.f ? o1 : 0.f;

    if (out16) {                                   // layer 1: bf16 for next GEMM
        ushort2 u2;
        u2.x = f2b(o0);
        u2.y = f2b(o1);
        *(ushort2*)(out16 + (size_t)node * D + lane * 2) = u2;
    } else {                                       // layer 2: d_out writes + fused head li
        *(float2*)(xout + (size_t)node * D + lane * 2) = make_float2(o0, o1);
        if (node < num_res[0])
            *(float2*)(sout + (size_t)node * D + lane * 2) = make_float2(o0, o1);
        float2 wv = *(const float2*)(w_lin + lane * 2);
        float part = fmaf(o0, wv.x, o1 * wv.y);
        for (int off = 32; off; off >>= 1) part += __shfl_xor(part, off);
        if (lane == 0) {
            float s = part + b_lin[0];
            if (resmask[node] == 0) s = -1000000000.0f;
            pr[node] = s;
        }
    }
}

// ---------------- head (no max pass: softmax is shift-invariant; li is O(1),
// masked li=-1e9 underflows expf to exactly 0) ----------------

__global__ void head_exp(float* __restrict__ pr, float* __restrict__ sumexp,
                         const int* __restrict__ resmask, float* __restrict__ maskf, int n) {
    int i = blockIdx.x * blockDim.x + threadIdx.x;
    float u = 0.f;
    if (i < n) {
        u = __expf(pr[i]);
        pr[i] = u;
        maskf[i] = (float)resmask[i];
    }
    float t = u;
    for (int off = 32; off; off >>= 1) t += __shfl_down(t, off);
    if ((threadIdx.x & 63) == 0) atomicAdd(sumexp, t);
}

__global__ void head_final(float* __restrict__ pr, const float* __restrict__ sumexp,
                           const float* __restrict__ res, float* __restrict__ loss_out, int n) {
    int i = blockIdx.x * blockDim.x + threadIdx.x;
    float lt = 0.f;
    if (i < n) {
        float p = pr[i] / (*sumexp);
        pr[i] = p;
        float pc = fminf(fmaxf(p, 1e-10f), 1.0f);
        lt = -logf(pc) * res[i];
    }
    float t = lt;
    for (int off = 32; off; off >>= 1) t += __shfl_down(t, off);
    if ((threadIdx.x & 63) == 0) atomicAdd(loss_out, t);
}

extern "C" void kernel_launch(void* const* d_in, const int* in_sizes, int n_in,
                              void* d_out, int out_size, void* d_ws, size_t ws_size,
                              hipStream_t stream) {
    const float* input_node = (const float*)d_in[0];
    const int*   inputad    = (const int*)d_in[1];
    const float* res        = (const float*)d_in[2];
    const int*   resmask    = (const int*)d_in[3];
    const int*   num_res    = (const int*)d_in[4];
    const float* W1     = (const float*)d_in[5];
    const float* a_src1 = (const float*)d_in[6];
    const float* a_dst1 = (const float*)d_in[7];
    const float* b1     = (const float*)d_in[8];
    const float* W2     = (const float*)d_in[9];
    const float* a_src2 = (const float*)d_in[10];
    const float* a_dst2 = (const float*)d_in[11];
    const float* b2     = (const float*)d_in[12];
    const float* w_lin  = (const float*)d_in[13];
    const float* b_lin  = (const float*)d_in[14];

    int n = in_sizes[0] / D;
    int E = in_sizes[1] / 2;
    int Et = E + n;
    int nbk = (n + 255) >> BSH;    // coarse buckets (dst>>8), <=256

    // workspace carve (16B aligned pieces)
    char* w = (char*)d_ws;
    unsigned short* xb16 = (unsigned short*)w; w += (size_t)n * D * 2;
    unsigned short* h16  = (unsigned short*)w; w += (size_t)n * D * 2;
    unsigned short* Wp1 = (unsigned short*)w; w += 16384 * 2;
    unsigned short* Wp2 = (unsigned short*)w; w += 16384 * 2;
    float* as_   = (float*)w; w += (size_t)n * 4;
    float* ad_   = (float*)w; w += (size_t)n * 4;
    int*   deg   = (int*)w;   w += (size_t)n * 4;
    int*   startv= (int*)w;   w += (size_t)n * 4;
    int*   csr_src=(int*)w;   w += (size_t)Et * 4;
    unsigned* pairbuf = (unsigned*)w; w += (size_t)Et * 4;
    int*   bcnt  = (int*)w;   w += 256 * CPAD * 4;
    int*   bcur  = (int*)w;   w += 256 * CPAD * 4;
    float* sumexp = (float*)w; w += 8;

    // d_out carve
    float* out0  = (float*)d_out;            // loss (1)
    float* prob  = out0 + 1;                 // N
    float* xout  = prob + n;                 // N*D
    float* maskf = xout + (size_t)n * D;     // N
    float* sout  = maskf + n;                // K*D

    dim3 blk(256);
    auto cdiv = [](long long a, long long b) { return (unsigned)((a + b - 1) / b); };
    unsigned nb = cdiv(n, 256);

    zero_init<<<32, blk, 0, stream>>>(bcnt, bcur, sumexp, out0);

    // ---- prep: chunked hist + conv + W packs (one kernel) ----
    int count8 = n * D / 8;
    unsigned nbconv = cdiv(count8, 256);
    unsigned nbhist = cdiv(Et, SCH);
    prep<<<nbhist + nbconv + 128, blk, 0, stream>>>(input_node, xb16, W1, Wp1, W2, Wp2,
                                                    inputad, E, n, bcnt, count8,
                                                    (int)nbconv, (int)nbhist);

    unsigned agg_grid = cdiv(n, 4);
    unsigned gemm_grid = cdiv(n, 64);

    // ---- fused: gemm layer-1 || bucket scatter ----
    gemm1_scatter<<<gemm_grid + nbhist, blk, SCAT_LDS, stream>>>(
        xb16, Wp1, a_src1, a_dst1, h16, as_, ad_,
        inputad, E, bcnt, bcur, pairbuf, nbk, n, (int)gemm_grid);

    // ---- csr build ----
    csr_build<<<nbk, blk, 0, stream>>>(pairbuf, bcnt, deg, startv, csr_src, nbk, n);

    // ---- Layer 1 aggregate ----
    gat_aggregate<<<agg_grid, blk, 0, stream>>>(csr_src, startv, deg, as_, ad_, h16, b1,
                                                xb16, nullptr, nullptr, nullptr, nullptr,
                                                nullptr, nullptr, nullptr, n);

    // ---- Layer 2 (writes straight into d_out; fused head li) ----
    gemm_mfma<<<gemm_grid, blk, GEMM_LDS, stream>>>(xb16, Wp2, a_src2, a_dst2, h16, as_, ad_, n);
    gat_aggregate<<<agg_grid, blk, 0, stream>>>(csr_src, startv, deg, as_, ad_, h16, b2,
                                                nullptr, xout, sout, w_lin, b_lin,
                                                resmask, prob, num_res, n);

    // ---- Head ----
    head_exp<<<nb, blk, 0, stream>>>(prob, sumexp, resmask, maskf, n);
    head_final<<<nb, blk, 0, stream>>>(prob, sumexp, res, out0, n);
}